// Round 1
// 514.337 us; speedup vs baseline: 1.0055x; 1.0055x over previous
//
#include <hip/hip_runtime.h>
#include <math.h>

// Problem constants (B=16, S=2048, L=E=512, N=2048)
#define BS_TOK 32768
#define DIM 512
#define NCODE 2048

typedef _Float16 f16x8 __attribute__((ext_vector_type(8)));
typedef _Float16 f16x4 __attribute__((ext_vector_type(4)));
typedef float f32x16 __attribute__((ext_vector_type(16)));

#define LDH 40  // halves per LDS row: 32 data + 8 pad = 80 B

// ---------------- row L2 normalize + fp16 hi/lo split ----------------
// one block (256 threads) per row of 512. Writes hi[t], lo[t] fp16 arrays
// (row stride rstride halves). Safe for in-place overwrite of `in` because
// all reads complete before the __syncthreads() that precedes writes.
__global__ __launch_bounds__(256) void k_rownorm_split(
    const float* __restrict__ in, _Float16* __restrict__ hi,
    _Float16* __restrict__ lo, int rstride) {
  const int r = blockIdx.x;
  const int t = threadIdx.x;
  const float* row = in + (size_t)r * DIM;
  float v0 = row[t];
  float v1 = row[t + 256];
  float s = v0 * v0 + v1 * v1;
#pragma unroll
  for (int off = 32; off > 0; off >>= 1) s += __shfl_down(s, off, 64);
  __shared__ float ls[4];
  if ((t & 63) == 0) ls[t >> 6] = s;
  __syncthreads();  // also fences: all global reads of this row are done
  float tot = ls[0] + ls[1] + ls[2] + ls[3];
  float sc = 1.0f / fmaxf(sqrtf(tot), 1e-12f);
  float x0 = v0 * sc, x1 = v1 * sc;
  _Float16 h0 = (_Float16)x0;
  _Float16 h1 = (_Float16)x1;
  _Float16 e0 = (_Float16)((x0 - (float)h0) * 2048.0f);
  _Float16 e1 = (_Float16)((x1 - (float)h1) * 2048.0f);
  _Float16* hrow = hi + (size_t)r * rstride;
  _Float16* lrow = lo + (size_t)r * rstride;
  hrow[t] = h0;
  hrow[t + 256] = h1;
  lrow[t] = e0;
  lrow[t + 256] = e1;
}

// ---------------- fp32 -> fp16 hi/lo elementwise split (weights) ------
__global__ __launch_bounds__(256) void k_split_w(const float* __restrict__ w,
                                                 _Float16* __restrict__ hi,
                                                 _Float16* __restrict__ lo) {
  int t = (blockIdx.x * 256 + threadIdx.x) * 4;
  float4 v = *(const float4*)(w + t);
  f16x4 h, l;
  h.x = (_Float16)v.x; l.x = (_Float16)((v.x - (float)h.x) * 2048.0f);
  h.y = (_Float16)v.y; l.y = (_Float16)((v.y - (float)h.y) * 2048.0f);
  h.z = (_Float16)v.z; l.z = (_Float16)((v.z - (float)h.z) * 2048.0f);
  h.w = (_Float16)v.w; l.w = (_Float16)((v.w - (float)h.w) * 2048.0f);
  *(f16x4*)(hi + t) = h;
  *(f16x4*)(lo + t) = l;
}

// ---------------- MFMA split GEMM: input projection -------------------
// C[m,n] = sum_k A[m,k]*B[n,k] + bias[n], A fp32 (split on the fly),
// B pre-split hi/lo fp16. Tile 128x128, BK=32, 4 waves 2x2, wave 64x64.
__global__ __launch_bounds__(256, 2) void k_gemm_mfma_in(
    const float* __restrict__ A, const _Float16* __restrict__ Bhi,
    const _Float16* __restrict__ Blo, const float* __restrict__ bias,
    float* __restrict__ C) {
  __shared__ __align__(16) _Float16 sm[4 * 128 * LDH];  // 40960 B
  _Float16* sAh = sm;
  _Float16* sAl = sm + 128 * LDH;
  _Float16* sBh = sm + 2 * 128 * LDH;
  _Float16* sBl = sm + 3 * 128 * LDH;
  const int tid = threadIdx.x;
  const int w = tid >> 6, l = tid & 63;
  const int wm = w >> 1, wn = w & 1;
  const int lm = l & 31, lh = l >> 5;
  const int m0 = blockIdx.y * 128;
  const int n0 = blockIdx.x * 128;
  f32x16 aHH[2][2], aX[2][2];
#pragma unroll
  for (int mb = 0; mb < 2; ++mb)
#pragma unroll
    for (int nb = 0; nb < 2; ++nb) {
      aHH[mb][nb] = (f32x16)0.0f;
      aX[mb][nb] = (f32x16)0.0f;
    }
  for (int ks = 0; ks < DIM; ks += 32) {
    __syncthreads();
    // stage A: 128 rows x 32 fp32 -> convert to hi/lo (4 float4/thread)
#pragma unroll
    for (int i = 0; i < 4; ++i) {
      int lin = tid + i * 256;
      int row = lin >> 3;
      int c4 = (lin & 7) << 2;
      float4 v = *(const float4*)(A + (size_t)(m0 + row) * DIM + ks + c4);
      f16x4 h, lo4;
      h.x = (_Float16)v.x; lo4.x = (_Float16)((v.x - (float)h.x) * 2048.0f);
      h.y = (_Float16)v.y; lo4.y = (_Float16)((v.y - (float)h.y) * 2048.0f);
      h.z = (_Float16)v.z; lo4.z = (_Float16)((v.z - (float)h.z) * 2048.0f);
      h.w = (_Float16)v.w; lo4.w = (_Float16)((v.w - (float)h.w) * 2048.0f);
      *(f16x4*)(&sAh[row * LDH + c4]) = h;
      *(f16x4*)(&sAl[row * LDH + c4]) = lo4;
    }
    // stage B: 128 rows x 32 halves hi+lo (2 f16x8/thread each)
#pragma unroll
    for (int i = 0; i < 2; ++i) {
      int lin = tid + i * 256;
      int row = lin >> 2;
      int q = (lin & 3) * 8;
      const size_t g = (size_t)(n0 + row) * DIM + ks + q;
      *(f16x8*)(&sBh[row * LDH + q]) = *(const f16x8*)(Bhi + g);
      *(f16x8*)(&sBl[row * LDH + q]) = *(const f16x8*)(Blo + g);
    }
    __syncthreads();
#pragma unroll
    for (int c = 0; c < 2; ++c) {
      const int ko = c * 16 + lh * 8;
      f16x8 ah[2], al[2], bh[2], bl[2];
#pragma unroll
      for (int mb = 0; mb < 2; ++mb) {
        int r = wm * 64 + mb * 32 + lm;
        ah[mb] = *(const f16x8*)(&sAh[r * LDH + ko]);
        al[mb] = *(const f16x8*)(&sAl[r * LDH + ko]);
      }
#pragma unroll
      for (int nb = 0; nb < 2; ++nb) {
        int r = wn * 64 + nb * 32 + lm;
        bh[nb] = *(const f16x8*)(&sBh[r * LDH + ko]);
        bl[nb] = *(const f16x8*)(&sBl[r * LDH + ko]);
      }
#pragma unroll
      for (int mb = 0; mb < 2; ++mb)
#pragma unroll
        for (int nb = 0; nb < 2; ++nb) {
          aHH[mb][nb] = __builtin_amdgcn_mfma_f32_32x32x16_f16(
              ah[mb], bh[nb], aHH[mb][nb], 0, 0, 0);
          aX[mb][nb] = __builtin_amdgcn_mfma_f32_32x32x16_f16(
              ah[mb], bl[nb], aX[mb][nb], 0, 0, 0);
          aX[mb][nb] = __builtin_amdgcn_mfma_f32_32x32x16_f16(
              al[mb], bh[nb], aX[mb][nb], 0, 0, 0);
        }
    }
  }
#pragma unroll
  for (int nb = 0; nb < 2; ++nb) {
    int n = n0 + wn * 64 + nb * 32 + lm;
    float bv = bias[n];
#pragma unroll
    for (int mb = 0; mb < 2; ++mb)
#pragma unroll
      for (int r = 0; r < 16; ++r) {
        int m = m0 + wm * 64 + mb * 32 + (r & 3) + 8 * (r >> 2) + 4 * lh;
        C[(size_t)m * DIM + n] =
            aHH[mb][nb][r] + aX[mb][nb][r] * (1.0f / 2048.0f) + bv;
      }
  }
}

// ---------------- MFMA split GEMM: gathered output projection ---------
// A rows = embhi/emblo[gather[m]]; epilogue does strict fp32
// straight-through: out = z + ((acc + bias) - z).
__global__ __launch_bounds__(256, 2) void k_gemm_mfma_gather(
    const _Float16* __restrict__ Ahi, const _Float16* __restrict__ Alo,
    const _Float16* __restrict__ Bhi, const _Float16* __restrict__ Blo,
    const float* __restrict__ bias, float* __restrict__ C,
    const int* __restrict__ gather, const float* __restrict__ zin) {
  __shared__ __align__(16) _Float16 sm[4 * 128 * LDH];
  __shared__ int gidx[128];
  _Float16* sAh = sm;
  _Float16* sAl = sm + 128 * LDH;
  _Float16* sBh = sm + 2 * 128 * LDH;
  _Float16* sBl = sm + 3 * 128 * LDH;
  const int tid = threadIdx.x;
  const int w = tid >> 6, l = tid & 63;
  const int wm = w >> 1, wn = w & 1;
  const int lm = l & 31, lh = l >> 5;
  const int m0 = blockIdx.y * 128;
  const int n0 = blockIdx.x * 128;
  if (tid < 128) gidx[tid] = gather[m0 + tid];
  f32x16 aHH[2][2], aX[2][2];
#pragma unroll
  for (int mb = 0; mb < 2; ++mb)
#pragma unroll
    for (int nb = 0; nb < 2; ++nb) {
      aHH[mb][nb] = (f32x16)0.0f;
      aX[mb][nb] = (f32x16)0.0f;
    }
  for (int ks = 0; ks < DIM; ks += 32) {
    __syncthreads();  // first iter also fences gidx
#pragma unroll
    for (int i = 0; i < 2; ++i) {
      int lin = tid + i * 256;
      int row = lin >> 2;
      int q = (lin & 3) * 8;
      const size_t ga = (size_t)gidx[row] * DIM + ks + q;
      *(f16x8*)(&sAh[row * LDH + q]) = *(const f16x8*)(Ahi + ga);
      *(f16x8*)(&sAl[row * LDH + q]) = *(const f16x8*)(Alo + ga);
      const size_t gb = (size_t)(n0 + row) * DIM + ks + q;
      *(f16x8*)(&sBh[row * LDH + q]) = *(const f16x8*)(Bhi + gb);
      *(f16x8*)(&sBl[row * LDH + q]) = *(const f16x8*)(Blo + gb);
    }
    __syncthreads();
#pragma unroll
    for (int c = 0; c < 2; ++c) {
      const int ko = c * 16 + lh * 8;
      f16x8 ah[2], al[2], bh[2], bl[2];
#pragma unroll
      for (int mb = 0; mb < 2; ++mb) {
        int r = wm * 64 + mb * 32 + lm;
        ah[mb] = *(const f16x8*)(&sAh[r * LDH + ko]);
        al[mb] = *(const f16x8*)(&sAl[r * LDH + ko]);
      }
#pragma unroll
      for (int nb = 0; nb < 2; ++nb) {
        int r = wn * 64 + nb * 32 + lm;
        bh[nb] = *(const f16x8*)(&sBh[r * LDH + ko]);
        bl[nb] = *(const f16x8*)(&sBl[r * LDH + ko]);
      }
#pragma unroll
      for (int mb = 0; mb < 2; ++mb)
#pragma unroll
        for (int nb = 0; nb < 2; ++nb) {
          aHH[mb][nb] = __builtin_amdgcn_mfma_f32_32x32x16_f16(
              ah[mb], bh[nb], aHH[mb][nb], 0, 0, 0);
          aX[mb][nb] = __builtin_amdgcn_mfma_f32_32x32x16_f16(
              ah[mb], bl[nb], aX[mb][nb], 0, 0, 0);
          aX[mb][nb] = __builtin_amdgcn_mfma_f32_32x32x16_f16(
              al[mb], bh[nb], aX[mb][nb], 0, 0, 0);
        }
    }
  }
#pragma unroll
  for (int nb = 0; nb < 2; ++nb) {
    int n = n0 + wn * 64 + nb * 32 + lm;
    float bv = bias[n];
#pragma unroll
    for (int mb = 0; mb < 2; ++mb)
#pragma unroll
      for (int r = 0; r < 16; ++r) {
        int m = m0 + wm * 64 + mb * 32 + (r & 3) + 8 * (r >> 2) + 4 * lh;
        float val = aHH[mb][nb][r] + aX[mb][nb][r] * (1.0f / 2048.0f) + bv;
        float zv = zin[(size_t)m * DIM + n];
        C[(size_t)m * DIM + n] = zv + (val - zv);
      }
  }
}

// ---------------- MFMA similarity + argmax ----------------------------
// Block: 128 tokens x 512 codes (grid 1024 = 256 mtiles x 4 code-quarters
// -> exactly 4 blocks/CU: LDS 4x40960 B = 160 KiB, VGPR ~96).
// 4 waves 2x2, wave-tile 64x64 via mfma_f32_32x32x16_f16.
// sim = acc_hh + acc_x/2048 (Markidis fp16 split, err ~1e-8).
// Cross-quarter combine via packed u64 atomicMax (monotone float | ~index),
// which preserves torch argmin's first-min-index tie-break exactly.
#define SIMK_BM 128
#define SIMK_BN 128
#define NQUART 4
#define QCODES (NCODE / NQUART)  // 512

// 16B-slot XOR swizzle: rows 8 apart alias banks at stride-80B (8*80 == 0
// mod 128B) -> 4-way ds_read_b128 conflict. XOR slot with row bits 3-4 so
// lanes {lm, lm+8, lm+16, lm+24} read 4 distinct 16B slots. Same involution
// on write and read.
__device__ __forceinline__ int swz8(int row, int slot) {
  return row * LDH + ((slot ^ ((row >> 3) & 3)) << 3);
}

__global__ __launch_bounds__(256, 2) void k_sim_argmax(
    const _Float16* __restrict__ Apack,  // token rows: 1024 halves = hi|lo
    const _Float16* __restrict__ Bhi, const _Float16* __restrict__ Blo,
    unsigned long long* __restrict__ keys) {
  __shared__ __align__(16) _Float16 sm[4 * 128 * LDH];  // 40960 B
  _Float16* sAh = sm;
  _Float16* sAl = sm + 128 * LDH;
  _Float16* sBh = sm + 2 * 128 * LDH;
  _Float16* sBl = sm + 3 * 128 * LDH;
  float* sC = (float*)sm;  // aliased: [128][65] fp32 = 33280 B

  const int tid = threadIdx.x;
  const int w = tid >> 6, l = tid & 63;
  const int wm = w >> 1, wn = w & 1;
  const int lm = l & 31, lh = l >> 5;
  const int q = blockIdx.x & (NQUART - 1);
  const int tokbase = (blockIdx.x >> 2) * SIMK_BM;
  const int code0 = q * QCODES;
  const int srow0 = tid >> 2, sq = tid & 3;
  const int t_red = tid >> 1, h_red = tid & 1;

  float bestv = -2.0f;
  int bestn = 0;

  for (int nt = 0; nt < QCODES; nt += SIMK_BN) {
    f32x16 aHH[2][2], aX[2][2];
#pragma unroll
    for (int mb = 0; mb < 2; ++mb)
#pragma unroll
      for (int nb = 0; nb < 2; ++nb) {
        aHH[mb][nb] = (f32x16)0.0f;
        aX[mb][nb] = (f32x16)0.0f;
      }
    for (int ks = 0; ks < DIM; ks += 32) {
      __syncthreads();
#pragma unroll
      for (int i = 0; i < 2; ++i) {
        int row = srow0 + i * 64;
        const _Float16* gA =
            Apack + (size_t)(tokbase + row) * 1024 + ks + sq * 8;
        *(f16x8*)(&sAh[swz8(row, sq)]) = *(const f16x8*)(gA);
        *(f16x8*)(&sAl[swz8(row, sq)]) = *(const f16x8*)(gA + 512);
        const size_t crow = (size_t)(code0 + nt + row) * DIM + ks + sq * 8;
        *(f16x8*)(&sBh[swz8(row, sq)]) = *(const f16x8*)(Bhi + crow);
        *(f16x8*)(&sBl[swz8(row, sq)]) = *(const f16x8*)(Blo + crow);
      }
      __syncthreads();
#pragma unroll
      for (int c = 0; c < 2; ++c) {
        const int slot = c * 2 + lh;
        f16x8 ah[2], al[2], bh[2], bl[2];
#pragma unroll
        for (int mb = 0; mb < 2; ++mb) {
          int r = wm * 64 + mb * 32 + lm;
          ah[mb] = *(const f16x8*)(&sAh[swz8(r, slot)]);
          al[mb] = *(const f16x8*)(&sAl[swz8(r, slot)]);
        }
#pragma unroll
        for (int nb = 0; nb < 2; ++nb) {
          int r = wn * 64 + nb * 32 + lm;
          bh[nb] = *(const f16x8*)(&sBh[swz8(r, slot)]);
          bl[nb] = *(const f16x8*)(&sBl[swz8(r, slot)]);
        }
#pragma unroll
        for (int mb = 0; mb < 2; ++mb)
#pragma unroll
          for (int nb = 0; nb < 2; ++nb) {
            aHH[mb][nb] = __builtin_amdgcn_mfma_f32_32x32x16_f16(
                ah[mb], bh[nb], aHH[mb][nb], 0, 0, 0);
            aX[mb][nb] = __builtin_amdgcn_mfma_f32_32x32x16_f16(
                ah[mb], bl[nb], aX[mb][nb], 0, 0, 0);
            aX[mb][nb] = __builtin_amdgcn_mfma_f32_32x32x16_f16(
                al[mb], bh[nb], aX[mb][nb], 0, 0, 0);
          }
      }
    }
    // epilogue: two n-halves through LDS (aliased over staging region)
#pragma unroll
    for (int p = 0; p < 2; ++p) {
      __syncthreads();
      if (wn == p) {
#pragma unroll
        for (int mb = 0; mb < 2; ++mb)
#pragma unroll
          for (int nb = 0; nb < 2; ++nb) {
            int nl = nb * 32 + lm;
#pragma unroll
            for (int r = 0; r < 16; ++r) {
              int m = wm * 64 + mb * 32 + (r & 3) + 8 * (r >> 2) + 4 * lh;
              float v = aHH[mb][nb][r] + aX[mb][nb][r] * (1.0f / 2048.0f);
              sC[m * 65 + nl] = v;
            }
          }
      }
      __syncthreads();
      const float* rowp = &sC[t_red * 65 + h_red * 32];
      int nbase = code0 + nt + p * 64 + h_red * 32;
#pragma unroll
      for (int i = 0; i < 32; ++i) {
        float v = rowp[i];
        if (v > bestv) {  // n scanned ascending: '>' keeps first occurrence
          bestv = v;
          bestn = nbase + i;
        }
      }
    }
  }
  // combine the two half-lanes for this token
  float ov = __shfl_xor(bestv, 1);
  int on = __shfl_xor(bestn, 1);
  if (ov > bestv || (ov == bestv && on < bestn)) {
    bestv = ov;
    bestn = on;
  }
  if (h_red == 0) {
    // monotone float encoding: larger key == larger value; low word
    // NCODE-1-n so equal values pick the smaller index (first occurrence).
    unsigned vb = __float_as_uint(bestv);
    vb = (vb & 0x80000000u) ? ~vb : (vb | 0x80000000u);
    unsigned long long key =
        ((unsigned long long)vb << 32) | (unsigned)(NCODE - 1 - bestn);
    atomicMax(&keys[tokbase + t_red], key);
  }
}

// ---------------- init packed argmax keys ----------------------------
__global__ __launch_bounds__(256) void k_init_keys(
    unsigned long long* __restrict__ keys) {
  keys[blockIdx.x * 256 + threadIdx.x] = 0ull;  // < any real encoded sim
}

// ---------------- decode packed keys -> idx (int) + idxf (float) ------
__global__ __launch_bounds__(256) void k_decode(
    const unsigned long long* __restrict__ keys, int* __restrict__ idx,
    float* __restrict__ idxf) {
  int t = blockIdx.x * 256 + threadIdx.x;
  int n = NCODE - 1 - (int)(keys[t] & 0xFFFFFFFFull);
  idx[t] = n;
  idxf[t] = (float)n;
}

extern "C" void kernel_launch(void* const* d_in, const int* in_sizes, int n_in,
                              void* d_out, int out_size, void* d_ws,
                              size_t ws_size, hipStream_t stream) {
  const float* z = (const float*)d_in[0];
  // d_in[1] = mask, unused
  const float* W_in = (const float*)d_in[2];
  const float* b_in = (const float*)d_in[3];
  const float* W_out = (const float*)d_in[4];
  const float* b_out = (const float*)d_in[5];
  const float* emb = (const float*)d_in[6];

  float* out = (float*)d_out;
  float* zq = out;                           // 32768*512 fp32 (final output)
  float* idxf = out + (size_t)BS_TOK * DIM;  // 32768 fp32 indices

  // ws layout (~6.4 MB): embhi|emblo|winhi|winlo|wouthi|woutlo|keys|idx
  _Float16* embhi = (_Float16*)d_ws;
  _Float16* emblo = embhi + (size_t)NCODE * DIM;
  _Float16* winhi = emblo + (size_t)NCODE * DIM;
  _Float16* winlo = winhi + (size_t)DIM * DIM;
  _Float16* wouthi = winlo + (size_t)DIM * DIM;
  _Float16* woutlo = wouthi + (size_t)DIM * DIM;
  unsigned long long* keys =
      (unsigned long long*)(woutlo + (size_t)DIM * DIM);  // 8B-aligned
  int* idx = (int*)(keys + (size_t)BS_TOK);

  // zf fp32 lives in the zq region; then packed in-place to fp16 hi|lo rows
  float* zf = zq;
  _Float16* zf16 = (_Float16*)zf;  // row stride 1024 halves: [hi 512|lo 512]

  // 0) init argmax keys + split weights
  k_init_keys<<<BS_TOK / 256, 256, 0, stream>>>(keys);
  k_split_w<<<DIM * DIM / 1024, 256, 0, stream>>>(W_in, winhi, winlo);
  k_split_w<<<DIM * DIM / 1024, 256, 0, stream>>>(W_out, wouthi, woutlo);
  // 1) normalize + split codebook rows -> ws
  k_rownorm_split<<<NCODE, 256, 0, stream>>>(emb, embhi, emblo, DIM);
  // 2) zf = z @ W_in^T + b_in (MFMA fp16-split, A converted on the fly)
  k_gemm_mfma_in<<<dim3(DIM / 128, BS_TOK / 128), 256, 0, stream>>>(
      z, winhi, winlo, b_in, zf);
  // 3) normalize zf rows, split to fp16 hi/lo IN-PLACE (packed rows)
  k_rownorm_split<<<BS_TOK, 256, 0, stream>>>(zf, zf16, zf16 + 512, 1024);
  // 4) MFMA similarity + argmax (4 code-quarters per token tile)
  k_sim_argmax<<<(BS_TOK / SIMK_BM) * NQUART, 256, 0, stream>>>(zf16, embhi,
                                                                emblo, keys);
  // 5) decode packed keys -> idx (ws) + idxf (d_out)
  k_decode<<<BS_TOK / 256, 256, 0, stream>>>(keys, idx, idxf);
  // 6) zq = emb_n[idx] @ W_out^T + b_out (+ straight-through), overwrites zf
  k_gemm_mfma_gather<<<dim3(DIM / 128, BS_TOK / 128), 256, 0, stream>>>(
      embhi, emblo, wouthi, woutlo, b_out, zq, idx, z);
}